// Round 1
// baseline (142.516 us; speedup 1.0000x reference)
//
#include <hip/hip_runtime.h>

// Problem constants (compile-time, from reference):
//   B=2, D=H=W=160, C=2, N_LABELS=25, MAX_LABEL=48
//   voxels/batch V = 160^3 = 4,096,000 ; total voxels = 8,192,000
#define VPB   4096000
#define NLAB  25
#define MAXL  48
#define TOTAL_VOX 8192000

// Inverse LUT: FreeSurfer label value -> row index in means/stds.
// GEN_LABELS = {0,2,3,4,5,7,8,10,11,12,13,14,15,16,17,18,24,26,28,41,42,43,44,46,47}
__device__ __constant__ int c_lut[MAXL] = {
    /* 0*/ 0, /* 1*/ 0, /* 2*/ 1, /* 3*/ 2, /* 4*/ 3, /* 5*/ 4, /* 6*/ 0, /* 7*/ 5,
    /* 8*/ 6, /* 9*/ 0, /*10*/ 7, /*11*/ 8, /*12*/ 9, /*13*/10, /*14*/11, /*15*/12,
    /*16*/13, /*17*/14, /*18*/15, /*19*/ 0, /*20*/ 0, /*21*/ 0, /*22*/ 0, /*23*/ 0,
    /*24*/16, /*25*/ 0, /*26*/17, /*27*/ 0, /*28*/18, /*29*/ 0, /*30*/ 0, /*31*/ 0,
    /*32*/ 0, /*33*/ 0, /*34*/ 0, /*35*/ 0, /*36*/ 0, /*37*/ 0, /*38*/ 0, /*39*/ 0,
    /*40*/ 0, /*41*/19, /*42*/20, /*43*/21, /*44*/22, /*45*/ 0, /*46*/23, /*47*/24
};

// One thread handles 4 consecutive voxels (8 output floats).
// Grid: 8000 blocks x 256 threads = 2,048,000 threads x 4 voxels = 8,192,000.
__global__ __launch_bounds__(256) void gmm_sample_kernel(
    const int*   __restrict__ labels,   // [B*V] (trailing dim 1 squeezed)
    const float* __restrict__ means,    // [B, 25, 2]
    const float* __restrict__ stds,     // [B, 25, 2]
    const float* __restrict__ noise,    // [B*V, 2]
    float*       __restrict__ out)      // [B*V, 2]
{
    // Fused per-(batch,label-value) table: (mean0, mean1, std0, std1).
    __shared__ float4 table[2 * MAXL];

    const int tid = threadIdx.x;
    if (tid < 2 * MAXL) {
        const int b = tid / MAXL;
        const int v = tid - b * MAXL;
        const int row = c_lut[v];
        const float* mp = means + ((b * NLAB + row) << 1);
        const float* sp = stds  + ((b * NLAB + row) << 1);
        table[tid] = make_float4(mp[0], mp[1], sp[0], sp[1]);
    }
    __syncthreads();

    const int g  = blockIdx.x * 256 + tid;      // thread id, < 2,048,000
    const int v0 = g << 2;                      // first voxel, < 8,192,000
    // Batch boundary (4,096,000) is a multiple of 4 -> all 4 voxels same batch.
    const int boff = (v0 >= VPB) ? MAXL : 0;

    const int4   lab = *(const int4*)  (labels + v0);
    const float4 n0  = *(const float4*)(noise + ((size_t)v0 << 1));
    const float4 n1  = *(const float4*)(noise + ((size_t)v0 << 1) + 4);

    const float4 e0 = table[boff + lab.x];
    const float4 e1 = table[boff + lab.y];
    const float4 e2 = table[boff + lab.z];
    const float4 e3 = table[boff + lab.w];

    float4 o0, o1;
    o0.x = fmaf(e0.z, n0.x, e0.x);
    o0.y = fmaf(e0.w, n0.y, e0.y);
    o0.z = fmaf(e1.z, n0.z, e1.x);
    o0.w = fmaf(e1.w, n0.w, e1.y);
    o1.x = fmaf(e2.z, n1.x, e2.x);
    o1.y = fmaf(e2.w, n1.y, e2.y);
    o1.z = fmaf(e3.z, n1.z, e3.x);
    o1.w = fmaf(e3.w, n1.w, e3.y);

    *(float4*)(out + ((size_t)v0 << 1))     = o0;
    *(float4*)(out + ((size_t)v0 << 1) + 4) = o1;
}

extern "C" void kernel_launch(void* const* d_in, const int* in_sizes, int n_in,
                              void* d_out, int out_size, void* d_ws, size_t ws_size,
                              hipStream_t stream) {
    const int*   labels = (const int*)  d_in[0];  // [2,160,160,160,1] int32
    const float* means  = (const float*)d_in[1];  // [2,25,2] f32
    const float* stds   = (const float*)d_in[2];  // [2,25,2] f32
    const float* noise  = (const float*)d_in[3];  // [2,160,160,160,2] f32
    float* out = (float*)d_out;                   // [2,160,160,160,2] f32

    const int threads = 256;
    const int total_threads = TOTAL_VOX / 4;      // 2,048,000
    const int blocks = total_threads / threads;   // 8000
    gmm_sample_kernel<<<blocks, threads, 0, stream>>>(labels, means, stds, noise, out);
}